// Round 1
// baseline (1718.673 us; speedup 1.0000x reference)
//
#include <hip/hip_runtime.h>
#include <hip/hip_bf16.h>

#define HD   64
#define SEQ  2048
#define NB   256
#define TWOH 128

// ws float layout:
// [0,4096)      k_tab  (normalized k per token)
// [4096,8192)   v_tab
// [8192,12288)  q_tab
// [12288,12352) thr    (0.4 * ||v_t||)
// [12352]       bf16 input flag (1.0f if inputs are bf16)

__device__ __forceinline__ float wave_sum(float v) {
    v += __shfl_xor(v, 1);
    v += __shfl_xor(v, 2);
    v += __shfl_xor(v, 4);
    v += __shfl_xor(v, 8);
    v += __shfl_xor(v, 16);
    v += __shfl_xor(v, 32);
    return v;  // all 64 lanes hold identical total (butterfly is exact-symmetric)
}

// f32 data read as bf16 at even 16-bit halves -> mantissa bits in exponent field
// -> huge/NaN values with ~44%/sample probability. True bf16 inputs are ~0.05-scale.
__device__ __forceinline__ bool detect_bf16(const void* embed) {
    const unsigned short* u = (const unsigned short*)embed;
    int bad = 0;
    for (int i = 2 * threadIdx.x; i < 4096; i += 128) {
        float v = __uint_as_float(((unsigned int)u[i]) << 16);
        if (!(fabsf(v) < 1e4f)) bad = 1;  // catches NaN too
    }
    return !__any(bad);
}

template <bool BF>
__device__ __forceinline__ float ldf(const void* p, int i) {
    if (BF) return __bfloat162float(((const __hip_bfloat16*)p)[i]);
    return ((const float*)p)[i];
}

template <bool BF>
__device__ void precompute_body(const void* embed, const void* w1, const void* b1,
                                const void* w2, const void* b2, const void* ln_g,
                                const void* ln_b, const void* wk, const void* wv,
                                const void* wq, float* __restrict__ ws) {
    const int t = blockIdx.x, d = threadIdx.x;   // one block per token, 64 lanes = dims
    __shared__ float sh_h[HD];
    __shared__ float sh_u[TWOH];

    float h = ldf<BF>(embed, t * HD + d);
    sh_h[d] = h;
    __syncthreads();

    // FFN layer 1: u = relu(h @ w1 + b1), lane handles e = d and d+64
    float u0 = ldf<BF>(b1, d), u1 = ldf<BF>(b1, d + HD);
    #pragma unroll 8
    for (int j = 0; j < HD; ++j) {
        float hj = sh_h[j];
        u0 = fmaf(hj, ldf<BF>(w1, j * TWOH + d), u0);
        u1 = fmaf(hj, ldf<BF>(w1, j * TWOH + d + HD), u1);
    }
    u0 = fmaxf(u0, 0.f);
    u1 = fmaxf(u1, 0.f);
    sh_u[d] = u0;
    sh_u[d + HD] = u1;
    __syncthreads();

    // FFN layer 2 + residual
    float ff = ldf<BF>(b2, d);
    #pragma unroll 8
    for (int e = 0; e < TWOH; ++e)
        ff = fmaf(sh_u[e], ldf<BF>(w2, e * HD + d), ff);
    float y = h + ff;

    // LayerNorm (mean/var over 64 dims, eps 1e-5)
    float mu  = wave_sum(y) * 0.015625f;
    float dv  = y - mu;
    float var = wave_sum(dv * dv) * 0.015625f;
    float hn  = fmaf(dv * (1.f / sqrtf(var + 1e-5f)), ldf<BF>(ln_g, d),
                     ldf<BF>(ln_b, d));

    __syncthreads();          // all lanes done reading sh_h as h
    sh_h[d] = hn;
    __syncthreads();

    // k/v/q projections
    float k = 0.f, v = 0.f, q = 0.f;
    #pragma unroll 8
    for (int j = 0; j < HD; ++j) {
        float hj = sh_h[j];
        k = fmaf(hj, ldf<BF>(wk, j * HD + d), k);
        v = fmaf(hj, ldf<BF>(wv, j * HD + d), v);
        q = fmaf(hj, ldf<BF>(wq, j * HD + d), q);
    }
    float nk = sqrtf(wave_sum(k * k));
    k /= fmaxf(nk, 1e-12f);                 // k / max(||k||, NORM_EPS)
    float nv = sqrtf(wave_sum(v * v));

    ws[t * HD + d]        = k;
    ws[4096 + t * HD + d] = v;
    ws[8192 + t * HD + d] = q;
    if (d == 0) ws[12288 + t] = 0.4f * nv;  // THR * ||v_t||
    if (t == 0 && d == 0) ws[12352] = BF ? 1.f : 0.f;
}

__global__ __launch_bounds__(64) void precompute_kernel(
    const void* embed, const void* w1, const void* b1, const void* w2,
    const void* b2, const void* ln_g, const void* ln_b, const void* wk,
    const void* wv, const void* wq, float* __restrict__ ws) {
    if (detect_bf16(embed))
        precompute_body<true>(embed, w1, b1, w2, b2, ln_g, ln_b, wk, wv, wq, ws);
    else
        precompute_body<false>(embed, w1, b1, w2, b2, ln_g, ln_b, wk, wv, wq, ws);
}

// One wave per batch. Lane i holds row i of M in 64 VGPRs.
__global__ __launch_bounds__(64, 1) void scan_kernel(
    const int* __restrict__ x, const float* __restrict__ ws,
    const void* __restrict__ wo, const void* __restrict__ bo,
    void* __restrict__ out) {
    const int b = blockIdx.x, lane = threadIdx.x;
    __shared__ __align__(16) float k_lds[4096];
    __shared__ __align__(16) float v_lds[4096];
    __shared__ float thr_lds[64];
    __shared__ float rd[64];

    #pragma unroll
    for (int i = 0; i < 16; ++i) {
        int o = i * 256 + lane * 4;
        *(float4*)&k_lds[o] = *(const float4*)&ws[o];
        *(float4*)&v_lds[o] = *(const float4*)&ws[4096 + o];
    }
    thr_lds[lane] = ws[12288 + lane];
    const bool bf = ws[12352] != 0.f;

    float m[HD];
    #pragma unroll
    for (int j = 0; j < HD; ++j) m[j] = 0.f;
    __syncthreads();

    const int* xr = x + b * SEQ;
    int chunk = xr[lane];                       // prefetch 64 tokens into VGPR
    for (int base = 0; base < SEQ; base += 64) {
        int nxt = 0;
        if (base + 64 < SEQ) nxt = xr[base + 64 + lane];  // hide next chunk's latency
        #pragma unroll 1
        for (int s = 0; s < 64; ++s) {
            const int t = __builtin_amdgcn_readlane(chunk, s);  // wave-uniform token
            const float* kr = &k_lds[t * HD];
            float p0 = 0.f, p1 = 0.f, p2 = 0.f, p3 = 0.f;
            #pragma unroll
            for (int j = 0; j < HD; j += 4) {   // pred_i = sum_j M[i][j] * k[j]
                p0 = fmaf(m[j + 0], kr[j + 0], p0);
                p1 = fmaf(m[j + 1], kr[j + 1], p1);
                p2 = fmaf(m[j + 2], kr[j + 2], p2);
                p3 = fmaf(m[j + 3], kr[j + 3], p3);
            }
            const float pred  = (p0 + p1) + (p2 + p3);
            const float delta = v_lds[t * HD + lane] - pred;
            const float nd2   = wave_sum(delta * delta);
            const int gate    = sqrtf(nd2) > thr_lds[t];
            if (__builtin_amdgcn_readfirstlane(gate)) {     // uniform branch
                #pragma unroll
                for (int j = 0; j < HD; ++j)
                    m[j] = fmaf(delta, kr[j], m[j]);        // M += delta (x) k
            }
        }
        chunk = nxt;
    }

    // read = relu(M @ q_tok[last token])
    const int tl = xr[SEQ - 1];
    const float* qr = &ws[8192 + tl * HD];
    float r0 = 0.f, r1 = 0.f, r2 = 0.f, r3 = 0.f;
    #pragma unroll
    for (int j = 0; j < HD; j += 4) {
        r0 = fmaf(m[j + 0], qr[j + 0], r0);
        r1 = fmaf(m[j + 1], qr[j + 1], r1);
        r2 = fmaf(m[j + 2], qr[j + 2], r2);
        r3 = fmaf(m[j + 3], qr[j + 3], r3);
    }
    rd[lane] = fmaxf((r0 + r1) + (r2 + r3), 0.f);
    __syncthreads();

    // out[b][c] = sum_i read[i] * wo[i][c] + bo[c]   (lane = c)
    if (bf) {
        float acc = __bfloat162float(((const __hip_bfloat16*)bo)[lane]);
        #pragma unroll 8
        for (int i = 0; i < HD; ++i)
            acc = fmaf(rd[i],
                       __bfloat162float(((const __hip_bfloat16*)wo)[i * HD + lane]),
                       acc);
        ((__hip_bfloat16*)out)[b * HD + lane] = __float2bfloat16(acc);
    } else {
        float acc = ((const float*)bo)[lane];
        #pragma unroll 8
        for (int i = 0; i < HD; ++i)
            acc = fmaf(rd[i], ((const float*)wo)[i * HD + lane], acc);
        ((float*)out)[b * HD + lane] = acc;
    }
}

extern "C" void kernel_launch(void* const* d_in, const int* in_sizes, int n_in,
                              void* d_out, int out_size, void* d_ws, size_t ws_size,
                              hipStream_t stream) {
    const int* x     = (const int*)d_in[0];
    const void* embed = d_in[1];
    const void* w1    = d_in[2];
    const void* b1    = d_in[3];
    const void* w2    = d_in[4];
    const void* b2    = d_in[5];
    const void* ln_g  = d_in[6];
    const void* ln_b  = d_in[7];
    const void* wk    = d_in[8];
    const void* wv    = d_in[9];
    const void* wq    = d_in[10];
    const void* wo    = d_in[11];
    const void* bo    = d_in[12];
    float* ws = (float*)d_ws;

    precompute_kernel<<<64, 64, 0, stream>>>(embed, w1, b1, w2, b2, ln_g, ln_b,
                                             wk, wv, wq, ws);
    scan_kernel<<<NB, 64, 0, stream>>>(x, ws, wo, bo, d_out);
}

// Round 2
// 1081.750 us; speedup vs baseline: 1.5888x; 1.5888x over previous
//
#include <hip/hip_runtime.h>
#include <hip/hip_bf16.h>

#define HD   64
#define SEQ  2048
#define NB   256
#define TWOH 128

// ws float layout:
// [0,4096)      k_tab  (normalized k per token)
// [4096,8192)   v_tab
// [8192,12288)  q_tab
// [12288,12352) thr2   ((0.4*||v_t||)^2)
// [12352]       bf16 input flag (1.0f if inputs are bf16)

// ---- DPP wave-total: sum across 64 lanes, result broadcast (via lane 63) ----
template <int CTRL>
__device__ __forceinline__ float dpp_add(float x) {
    int y = __builtin_amdgcn_update_dpp(0, __builtin_bit_cast(int, x),
                                        CTRL, 0xF, 0xF, true);
    return x + __builtin_bit_cast(float, y);
}

__device__ __forceinline__ float wave_total(float x) {
    x = dpp_add<0x111>(x);   // row_shr:1
    x = dpp_add<0x112>(x);   // row_shr:2
    x = dpp_add<0x114>(x);   // row_shr:4
    x = dpp_add<0x118>(x);   // row_shr:8  -> lane15 of each row has row sum
    x = dpp_add<0x142>(x);   // row_bcast:15
    x = dpp_add<0x143>(x);   // row_bcast:31 -> lane 63 has full sum
    return __builtin_bit_cast(float,
        __builtin_amdgcn_readlane(__builtin_bit_cast(int, x), 63));
}

// f32 data read as bf16 at even 16-bit halves -> mantissa bits land in the
// exponent field -> huge/NaN values. True bf16 inputs are ~0.05-scale.
__device__ __forceinline__ bool detect_bf16(const void* embed) {
    const unsigned short* u = (const unsigned short*)embed;
    int bad = 0;
    for (int i = 2 * threadIdx.x; i < 4096; i += 128) {
        float v = __uint_as_float(((unsigned int)u[i]) << 16);
        if (!(fabsf(v) < 1e4f)) bad = 1;
    }
    return !__any(bad);
}

template <bool BF>
__device__ __forceinline__ float ldf(const void* p, int i) {
    if (BF) return __bfloat162float(((const __hip_bfloat16*)p)[i]);
    return ((const float*)p)[i];
}

template <bool BF>
__device__ void precompute_body(const void* embed, const void* w1, const void* b1,
                                const void* w2, const void* b2, const void* ln_g,
                                const void* ln_b, const void* wk, const void* wv,
                                const void* wq, float* __restrict__ ws) {
    const int t = blockIdx.x, d = threadIdx.x;   // one block per token, lanes = dims
    __shared__ float sh_h[HD];
    __shared__ float sh_u[TWOH];

    float h = ldf<BF>(embed, t * HD + d);        // h = embed[t] (token-only dep)
    sh_h[d] = h;
    __syncthreads();

    // FFN layer 1: u = relu(h @ w1 + b1); lane handles outputs d and d+64.
    float a0 = 0.f, a1 = 0.f, a2 = 0.f, a3 = 0.f;   // 2 partials per output
    #pragma unroll 16
    for (int j = 0; j < HD; j += 2) {
        float h0 = sh_h[j], h1 = sh_h[j + 1];
        a0 = fmaf(h0, ldf<BF>(w1, j * TWOH + d), a0);
        a1 = fmaf(h0, ldf<BF>(w1, j * TWOH + d + HD), a1);
        a2 = fmaf(h1, ldf<BF>(w1, (j + 1) * TWOH + d), a2);
        a3 = fmaf(h1, ldf<BF>(w1, (j + 1) * TWOH + d + HD), a3);
    }
    float u0 = fmaxf(a0 + a2 + ldf<BF>(b1, d), 0.f);
    float u1 = fmaxf(a1 + a3 + ldf<BF>(b1, d + HD), 0.f);
    sh_u[d] = u0;
    sh_u[d + HD] = u1;
    __syncthreads();

    // FFN layer 2 + residual (4 partial chains for ILP)
    float f0 = 0.f, f1 = 0.f, f2 = 0.f, f3 = 0.f;
    #pragma unroll 16
    for (int e = 0; e < TWOH; e += 4) {
        f0 = fmaf(sh_u[e + 0], ldf<BF>(w2, (e + 0) * HD + d), f0);
        f1 = fmaf(sh_u[e + 1], ldf<BF>(w2, (e + 1) * HD + d), f1);
        f2 = fmaf(sh_u[e + 2], ldf<BF>(w2, (e + 2) * HD + d), f2);
        f3 = fmaf(sh_u[e + 3], ldf<BF>(w2, (e + 3) * HD + d), f3);
    }
    float y = h + (f0 + f1) + (f2 + f3) + ldf<BF>(b2, d);

    // LayerNorm over 64 dims (eps 1e-5), DPP reductions
    float mu  = wave_total(y) * 0.015625f;
    float dv  = y - mu;
    float var = wave_total(dv * dv) * 0.015625f;
    float hn  = fmaf(dv * (1.f / sqrtf(var + 1e-5f)), ldf<BF>(ln_g, d),
                     ldf<BF>(ln_b, d));

    __syncthreads();
    sh_h[d] = hn;
    __syncthreads();

    // k/v/q projections (6 partial chains)
    float k0 = 0.f, k1 = 0.f, v0 = 0.f, v1 = 0.f, q0 = 0.f, q1 = 0.f;
    #pragma unroll 16
    for (int j = 0; j < HD; j += 2) {
        float h0 = sh_h[j], h1 = sh_h[j + 1];
        k0 = fmaf(h0, ldf<BF>(wk, j * HD + d), k0);
        v0 = fmaf(h0, ldf<BF>(wv, j * HD + d), v0);
        q0 = fmaf(h0, ldf<BF>(wq, j * HD + d), q0);
        k1 = fmaf(h1, ldf<BF>(wk, (j + 1) * HD + d), k1);
        v1 = fmaf(h1, ldf<BF>(wv, (j + 1) * HD + d), v1);
        q1 = fmaf(h1, ldf<BF>(wq, (j + 1) * HD + d), q1);
    }
    float k = k0 + k1, v = v0 + v1, q = q0 + q1;
    float nk = sqrtf(wave_total(k * k));
    k /= fmaxf(nk, 1e-12f);                 // k / max(||k||, NORM_EPS)
    float nv2 = wave_total(v * v);

    ws[t * HD + d]        = k;
    ws[4096 + t * HD + d] = v;
    ws[8192 + t * HD + d] = q;
    if (d == 0) ws[12288 + t] = 0.16f * nv2;   // (0.4*||v||)^2
    if (t == 0 && d == 0) ws[12352] = BF ? 1.f : 0.f;
}

__global__ __launch_bounds__(64) void precompute_kernel(
    const void* embed, const void* w1, const void* b1, const void* w2,
    const void* b2, const void* ln_g, const void* ln_b, const void* wk,
    const void* wv, const void* wq, float* __restrict__ ws) {
    if (detect_bf16(embed))
        precompute_body<true>(embed, w1, b1, w2, b2, ln_g, ln_b, wk, wv, wq, ws);
    else
        precompute_body<false>(embed, w1, b1, w2, b2, ln_g, ln_b, wk, wv, wq, ws);
}

// One wave per batch. Lane i holds row i of M in 64 VGPRs.
//
// Skip logic: k is unit-norm, so after an update M'=M+delta(x)k, the same
// token's next delta is delta*(1-||k||^2) ~ 6e-8*delta -> gate false. An
// un-gated check leaves M unchanged -> deterministic recheck is false again.
// So a token whose bit is set in `clean` provably cannot fire: skip it.
__global__ __launch_bounds__(64, 1) void scan_kernel(
    const int* __restrict__ x, const float* __restrict__ ws,
    const void* __restrict__ wo, const void* __restrict__ bo,
    void* __restrict__ out) {
    const int b = blockIdx.x, lane = threadIdx.x;
    __shared__ __align__(16) float k_lds[4096];
    __shared__ __align__(16) float v_lds[4096];
    __shared__ float rd[64];

    #pragma unroll
    for (int i = 0; i < 16; ++i) {
        int o = i * 256 + lane * 4;
        *(float4*)&k_lds[o] = *(const float4*)&ws[o];
        *(float4*)&v_lds[o] = *(const float4*)&ws[4096 + o];
    }
    const float thr2_reg = ws[12288 + lane];     // thr^2 for token==lane
    const bool bf = ws[12352] != 0.f;

    float m[HD];
    #pragma unroll
    for (int j = 0; j < HD; ++j) m[j] = 0.f;
    unsigned long long clean = 0;                // bit t: token t cannot fire
    __syncthreads();

    const int* xr = x + b * SEQ;
    int chunk = xr[lane];                        // 64 tokens in a VGPR
    for (int base = 0; base < SEQ; base += 64) {
        int nxt = 0;
        if (base + 64 < SEQ) nxt = xr[base + 64 + lane];
        // steps in this chunk whose token is dirty
        unsigned long long pend = __ballot(!((clean >> chunk) & 1ull));
        while (pend) {
            const int s = __builtin_ctzll(pend);
            const int t = __builtin_amdgcn_readlane(chunk, s);   // uniform
            const float vt = v_lds[t * HD + lane];
            float kr[HD];
            #pragma unroll
            for (int j = 0; j < HD; j += 4)
                *(float4*)&kr[j] = *(const float4*)&k_lds[t * HD + j];
            float p0 = 0.f, p1 = 0.f, p2 = 0.f, p3 = 0.f;
            #pragma unroll
            for (int j = 0; j < HD; j += 4) {    // pred_i = sum_j M[i][j]*k[j]
                p0 = fmaf(m[j + 0], kr[j + 0], p0);
                p1 = fmaf(m[j + 1], kr[j + 1], p1);
                p2 = fmaf(m[j + 2], kr[j + 2], p2);
                p3 = fmaf(m[j + 3], kr[j + 3], p3);
            }
            const float delta = vt - ((p0 + p1) + (p2 + p3));
            const float nd2   = wave_total(delta * delta);
            const float th2   = __builtin_bit_cast(float,
                __builtin_amdgcn_readlane(__builtin_bit_cast(int, thr2_reg), t));
            if (nd2 > th2) {                     // fire (uniform)
                #pragma unroll
                for (int j = 0; j < HD; ++j)
                    m[j] = fmaf(delta, kr[j], m[j]);
                clean = 1ull << t;               // everything else is dirty now
                const unsigned long long gt =
                    (s == 63) ? 0ull : (~0ull << (s + 1));
                pend = __ballot(chunk != t) & gt;
            } else {                             // no fire: t proven clean
                clean |= 1ull << t;
                pend &= ~__ballot(chunk == t);   // drop all later steps of t
            }
        }
        chunk = nxt;
    }

    // read = relu(M @ q_tok[last token])
    const int tl = xr[SEQ - 1];
    const float* qr = &ws[8192 + tl * HD];
    float r0 = 0.f, r1 = 0.f, r2 = 0.f, r3 = 0.f;
    #pragma unroll
    for (int j = 0; j < HD; j += 4) {
        r0 = fmaf(m[j + 0], qr[j + 0], r0);
        r1 = fmaf(m[j + 1], qr[j + 1], r1);
        r2 = fmaf(m[j + 2], qr[j + 2], r2);
        r3 = fmaf(m[j + 3], qr[j + 3], r3);
    }
    rd[lane] = fmaxf((r0 + r1) + (r2 + r3), 0.f);
    __syncthreads();

    // out[b][c] = sum_i read[i] * wo[i][c] + bo[c]   (lane = c)
    if (bf) {
        float acc = __bfloat162float(((const __hip_bfloat16*)bo)[lane]);
        #pragma unroll 8
        for (int i = 0; i < HD; ++i)
            acc = fmaf(rd[i],
                       __bfloat162float(((const __hip_bfloat16*)wo)[i * HD + lane]),
                       acc);
        ((__hip_bfloat16*)out)[b * HD + lane] = __float2bfloat16(acc);
    } else {
        float acc = ((const float*)bo)[lane];
        #pragma unroll 8
        for (int i = 0; i < HD; ++i)
            acc = fmaf(rd[i], ((const float*)wo)[i * HD + lane], acc);
        ((float*)out)[b * HD + lane] = acc;
    }
}

extern "C" void kernel_launch(void* const* d_in, const int* in_sizes, int n_in,
                              void* d_out, int out_size, void* d_ws, size_t ws_size,
                              hipStream_t stream) {
    const int* x      = (const int*)d_in[0];
    const void* embed = d_in[1];
    const void* w1    = d_in[2];
    const void* b1    = d_in[3];
    const void* w2    = d_in[4];
    const void* b2    = d_in[5];
    const void* ln_g  = d_in[6];
    const void* ln_b  = d_in[7];
    const void* wk    = d_in[8];
    const void* wv    = d_in[9];
    const void* wq    = d_in[10];
    const void* wo    = d_in[11];
    const void* bo    = d_in[12];
    float* ws = (float*)d_ws;

    precompute_kernel<<<64, 64, 0, stream>>>(embed, w1, b1, w2, b2, ln_g, ln_b,
                                             wk, wv, wq, ws);
    scan_kernel<<<NB, 64, 0, stream>>>(x, ws, wo, bo, d_out);
}

// Round 3
// 439.862 us; speedup vs baseline: 3.9073x; 2.4593x over previous
//
#include <hip/hip_runtime.h>
#include <hip/hip_bf16.h>

#define HD   64
#define SEQ  2048
#define NB   256
#define TWOH 128
#define NCH  32   // SEQ / 64

// ws float layout:
// [0,4096)      k_tab  (normalized k per token)
// [4096,8192)   v_tab
// [8192,12288)  q_tab
// [12288,12352) thr2   ((0.4*||v_t||)^2)
// [12352]       bf16 input flag
// [12416,16512) G = K K^T  (Gram of normalized keys)

#define WS_V    4096
#define WS_Q    8192
#define WS_THR  12288
#define WS_FLAG 12352
#define WS_G    12416

// ---- DPP wave-total: sum across 64 lanes, broadcast via lane 63 ----
template <int CTRL>
__device__ __forceinline__ float dpp_add(float x) {
    int y = __builtin_amdgcn_update_dpp(0, __builtin_bit_cast(int, x),
                                        CTRL, 0xF, 0xF, true);
    return x + __builtin_bit_cast(float, y);
}

__device__ __forceinline__ float wave_total(float x) {
    x = dpp_add<0x111>(x);   // row_shr:1
    x = dpp_add<0x112>(x);   // row_shr:2
    x = dpp_add<0x114>(x);   // row_shr:4
    x = dpp_add<0x118>(x);   // row_shr:8
    x = dpp_add<0x142>(x);   // row_bcast:15
    x = dpp_add<0x143>(x);   // row_bcast:31 -> lane 63 has full sum
    return __builtin_bit_cast(float,
        __builtin_amdgcn_readlane(__builtin_bit_cast(int, x), 63));
}

__device__ __forceinline__ float bcastf(float v, int l) {
    return __builtin_bit_cast(float,
        __builtin_amdgcn_readlane(__builtin_bit_cast(int, v), l));
}

// f32 data read as bf16 at even 16-bit halves -> mantissa bits land in the
// exponent field -> huge/NaN values. True bf16 inputs are ~0.05-scale.
__device__ __forceinline__ bool detect_bf16(const void* embed) {
    const unsigned short* u = (const unsigned short*)embed;
    int bad = 0;
    for (int i = 2 * threadIdx.x; i < 4096; i += 128) {
        float v = __uint_as_float(((unsigned int)u[i]) << 16);
        if (!(fabsf(v) < 1e4f)) bad = 1;
    }
    return !__any(bad);
}

template <bool BF>
__device__ __forceinline__ float ldf(const void* p, int i) {
    if (BF) return __bfloat162float(((const __hip_bfloat16*)p)[i]);
    return ((const float*)p)[i];
}

template <bool BF>
__device__ void precompute_body(const void* embed, const void* w1, const void* b1,
                                const void* w2, const void* b2, const void* ln_g,
                                const void* ln_b, const void* wk, const void* wv,
                                const void* wq, float* __restrict__ ws) {
    const int t = blockIdx.x, d = threadIdx.x;   // block = token, lanes = dims
    __shared__ float sh_h[HD];
    __shared__ float sh_u[TWOH];

    float h = ldf<BF>(embed, t * HD + d);
    sh_h[d] = h;
    __syncthreads();

    float a0 = 0.f, a1 = 0.f, a2 = 0.f, a3 = 0.f;
    #pragma unroll 16
    for (int j = 0; j < HD; j += 2) {
        float h0 = sh_h[j], h1 = sh_h[j + 1];
        a0 = fmaf(h0, ldf<BF>(w1, j * TWOH + d), a0);
        a1 = fmaf(h0, ldf<BF>(w1, j * TWOH + d + HD), a1);
        a2 = fmaf(h1, ldf<BF>(w1, (j + 1) * TWOH + d), a2);
        a3 = fmaf(h1, ldf<BF>(w1, (j + 1) * TWOH + d + HD), a3);
    }
    float u0 = fmaxf(a0 + a2 + ldf<BF>(b1, d), 0.f);
    float u1 = fmaxf(a1 + a3 + ldf<BF>(b1, d + HD), 0.f);
    sh_u[d] = u0;
    sh_u[d + HD] = u1;
    __syncthreads();

    float f0 = 0.f, f1 = 0.f, f2 = 0.f, f3 = 0.f;
    #pragma unroll 16
    for (int e = 0; e < TWOH; e += 4) {
        f0 = fmaf(sh_u[e + 0], ldf<BF>(w2, (e + 0) * HD + d), f0);
        f1 = fmaf(sh_u[e + 1], ldf<BF>(w2, (e + 1) * HD + d), f1);
        f2 = fmaf(sh_u[e + 2], ldf<BF>(w2, (e + 2) * HD + d), f2);
        f3 = fmaf(sh_u[e + 3], ldf<BF>(w2, (e + 3) * HD + d), f3);
    }
    float y = h + (f0 + f1) + (f2 + f3) + ldf<BF>(b2, d);

    float mu  = wave_total(y) * 0.015625f;
    float dv  = y - mu;
    float var = wave_total(dv * dv) * 0.015625f;
    float hn  = fmaf(dv * (1.f / sqrtf(var + 1e-5f)), ldf<BF>(ln_g, d),
                     ldf<BF>(ln_b, d));

    __syncthreads();
    sh_h[d] = hn;
    __syncthreads();

    float k0 = 0.f, k1 = 0.f, v0 = 0.f, v1 = 0.f, q0 = 0.f, q1 = 0.f;
    #pragma unroll 16
    for (int j = 0; j < HD; j += 2) {
        float h0 = sh_h[j], h1 = sh_h[j + 1];
        k0 = fmaf(h0, ldf<BF>(wk, j * HD + d), k0);
        v0 = fmaf(h0, ldf<BF>(wv, j * HD + d), v0);
        q0 = fmaf(h0, ldf<BF>(wq, j * HD + d), q0);
        k1 = fmaf(h1, ldf<BF>(wk, (j + 1) * HD + d), k1);
        v1 = fmaf(h1, ldf<BF>(wv, (j + 1) * HD + d), v1);
        q1 = fmaf(h1, ldf<BF>(wq, (j + 1) * HD + d), q1);
    }
    float k = k0 + k1, v = v0 + v1, q = q0 + q1;
    float nk = sqrtf(wave_total(k * k));
    k /= fmaxf(nk, 1e-12f);
    float nv2 = wave_total(v * v);

    ws[t * HD + d]        = k;
    ws[WS_V + t * HD + d] = v;
    ws[WS_Q + t * HD + d] = q;
    if (d == 0) ws[WS_THR + t] = 0.16f * nv2;   // (0.4*||v||)^2
    if (t == 0 && d == 0) ws[WS_FLAG] = BF ? 1.f : 0.f;
}

__global__ __launch_bounds__(64) void precompute_kernel(
    const void* embed, const void* w1, const void* b1, const void* w2,
    const void* b2, const void* ln_g, const void* ln_b, const void* wk,
    const void* wv, const void* wq, float* __restrict__ ws) {
    if (detect_bf16(embed))
        precompute_body<true>(embed, w1, b1, w2, b2, ln_g, ln_b, wk, wv, wq, ws);
    else
        precompute_body<false>(embed, w1, b1, w2, b2, ln_g, ln_b, wk, wv, wq, ws);
}

// G[t][u] = k_t . k_u  (block t, lane u). Reads k_tab, writes G region.
__global__ __launch_bounds__(64) void gram_kernel(float* __restrict__ ws) {
    const int t = blockIdx.x, u = threadIdx.x;
    __shared__ float kt[HD];
    kt[u] = ws[t * HD + u];
    __syncthreads();
    const float* kr = ws + u * HD;   // k_u row (L2-hot)
    float g0 = 0.f, g1 = 0.f, g2 = 0.f, g3 = 0.f;
    #pragma unroll
    for (int j = 0; j < HD; j += 4) {
        float4 kv = *(const float4*)&kr[j];
        g0 = fmaf(kt[j + 0], kv.x, g0);
        g1 = fmaf(kt[j + 1], kv.y, g1);
        g2 = fmaf(kt[j + 2], kv.z, g2);
        g3 = fmaf(kt[j + 3], kv.w, g3);
    }
    ws[WS_G + t * HD + u] = (g0 + g1) + (g2 + g3);
}

// One wave per batch. Lane t owns token t:
//   dv[0..63] = v_t - M k_t   (residual vector, incrementally maintained)
//   d[0..63]  = accumulated deltas fired on token t  (M = sum_t d_t (x) k_t)
//   nd2       = ||dv||^2  -> fireset = ballot(nd2 > thr2) covers ALL tokens.
// Stream steps whose token is not in fireset are exact no-ops (skipped).
// Fire on t: dv_u -= G[t][u] * delta_t for all u (delta_t broadcast via
// readlane); d_t += delta_t.
__global__ __launch_bounds__(64, 1) void scan_kernel(
    const int* __restrict__ x, const float* __restrict__ ws,
    const void* __restrict__ wo, const void* __restrict__ bo,
    void* __restrict__ out) {
    const int b = blockIdx.x, lane = threadIdx.x;
    __shared__ __align__(16) float smem[4160];   // G [t*64+u]; epilogue stride-65
    __shared__ int   tok_lds[SEQ];
    __shared__ float rd_lds[HD];

    // stage G and the token stream (coalesced)
    #pragma unroll
    for (int i = 0; i < 16; ++i) {
        int o = i * 256 + lane * 4;
        *(float4*)&smem[o] = *(const float4*)&ws[WS_G + o];
    }
    const int* xr = x + b * SEQ;
    #pragma unroll
    for (int c = 0; c < NCH; ++c) tok_lds[c * 64 + lane] = xr[c * 64 + lane];

    const float thr2 = ws[WS_THR + lane];
    const bool  bf   = ws[WS_FLAG] != 0.f;

    // dv = v_lane (M = 0), d = 0
    float dv[HD], d[HD];
    const float* vr = ws + WS_V + lane * HD;
    #pragma unroll
    for (int j = 0; j < HD; j += 4) {
        float4 vv = *(const float4*)&vr[j];
        dv[j] = vv.x; dv[j + 1] = vv.y; dv[j + 2] = vv.z; dv[j + 3] = vv.w;
        d[j] = 0.f; d[j + 1] = 0.f; d[j + 2] = 0.f; d[j + 3] = 0.f;
    }
    float p0 = 0.f, p1 = 0.f, p2 = 0.f, p3 = 0.f;
    #pragma unroll
    for (int j = 0; j < HD; j += 4) {
        p0 = fmaf(dv[j + 0], dv[j + 0], p0);
        p1 = fmaf(dv[j + 1], dv[j + 1], p1);
        p2 = fmaf(dv[j + 2], dv[j + 2], p2);
        p3 = fmaf(dv[j + 3], dv[j + 3], p3);
    }
    float nd2 = (p0 + p1) + (p2 + p3);
    __syncthreads();
    unsigned long long fireset = __ballot(nd2 > thr2);

    int chunk = tok_lds[lane];                   // software-pipelined chunk regs
    #pragma unroll 1
    for (int c = 0; c < NCH; ++c) {
        int nxt = 0;
        if (c + 1 < NCH) nxt = tok_lds[(c + 1) * 64 + lane];
        unsigned long long pend =
            __ballot((int)((fireset >> chunk) & 1ull));
        while (pend) {
            const int s = __builtin_ctzll(pend);
            const int t = __builtin_amdgcn_readlane(chunk, s);
            const float g   = smem[t * HD + lane];       // G[t][lane]
            const float sel = (lane == t) ? 1.f : 0.f;
            float q0 = 0.f, q1 = 0.f, q2 = 0.f, q3 = 0.f;
            #pragma unroll
            for (int j = 0; j < HD; j += 4) {
                float s0 = bcastf(dv[j + 0], t);         // delta_t components
                float s1 = bcastf(dv[j + 1], t);
                float s2 = bcastf(dv[j + 2], t);
                float s3 = bcastf(dv[j + 3], t);
                d[j + 0] = fmaf(sel, dv[j + 0], d[j + 0]);   // d_t += delta
                d[j + 1] = fmaf(sel, dv[j + 1], d[j + 1]);
                d[j + 2] = fmaf(sel, dv[j + 2], d[j + 2]);
                d[j + 3] = fmaf(sel, dv[j + 3], d[j + 3]);
                dv[j + 0] = fmaf(-g, s0, dv[j + 0]);         // dv_u -= G[t][u]*delta
                dv[j + 1] = fmaf(-g, s1, dv[j + 1]);
                dv[j + 2] = fmaf(-g, s2, dv[j + 2]);
                dv[j + 3] = fmaf(-g, s3, dv[j + 3]);
                q0 = fmaf(dv[j + 0], dv[j + 0], q0);         // new ||dv||^2
                q1 = fmaf(dv[j + 1], dv[j + 1], q1);
                q2 = fmaf(dv[j + 2], dv[j + 2], q2);
                q3 = fmaf(dv[j + 3], dv[j + 3], q3);
            }
            nd2 = (q0 + q1) + (q2 + q3);
            fireset = __ballot(nd2 > thr2);
            const unsigned long long above =
                (s >= 63) ? 0ull : (~0ull << (s + 1));
            pend = __ballot((int)((fireset >> chunk) & 1ull)) & above;
        }
        chunk = nxt;
    }

    // ---- epilogue: read = relu(M q_tl) = relu(sum_u (k_u.q) d_u) ----
    const int tl = xr[SEQ - 1];
    const float* qrow = ws + WS_Q + tl * HD;     // uniform (scalar) reads
    const float* krow = ws + lane * HD;          // k_lane row
    float c0 = 0.f, c1 = 0.f, c2 = 0.f, c3 = 0.f;
    #pragma unroll
    for (int j = 0; j < HD; j += 4) {
        float4 kv = *(const float4*)&krow[j];
        c0 = fmaf(qrow[j + 0], kv.x, c0);
        c1 = fmaf(qrow[j + 1], kv.y, c1);
        c2 = fmaf(qrow[j + 2], kv.z, c2);
        c3 = fmaf(qrow[j + 3], kv.w, c3);
    }
    const float cq = (c0 + c1) + (c2 + c3);      // k_lane . q
    __syncthreads();                             // done with G region
    #pragma unroll
    for (int j = 0; j < HD; ++j) smem[lane * 65 + j] = cq * d[j];
    __syncthreads();
    float r0 = 0.f, r1 = 0.f;
    #pragma unroll
    for (int u = 0; u < HD; u += 2) {
        r0 += smem[u * 65 + lane];
        r1 += smem[(u + 1) * 65 + lane];
    }
    rd_lds[lane] = fmaxf(r0 + r1, 0.f);
    __syncthreads();

    // out[b][c] = sum_i read[i] * wo[i][c] + bo[c]   (lane = c)
    if (bf) {
        float acc = __bfloat162float(((const __hip_bfloat16*)bo)[lane]);
        #pragma unroll 8
        for (int i = 0; i < HD; ++i)
            acc = fmaf(rd_lds[i],
                       __bfloat162float(((const __hip_bfloat16*)wo)[i * HD + lane]),
                       acc);
        ((__hip_bfloat16*)out)[b * HD + lane] = __float2bfloat16(acc);
    } else {
        float acc = ((const float*)bo)[lane];
        #pragma unroll 8
        for (int i = 0; i < HD; ++i)
            acc = fmaf(rd_lds[i], ((const float*)wo)[i * HD + lane], acc);
        ((float*)out)[b * HD + lane] = acc;
    }
}

extern "C" void kernel_launch(void* const* d_in, const int* in_sizes, int n_in,
                              void* d_out, int out_size, void* d_ws, size_t ws_size,
                              hipStream_t stream) {
    const int* x      = (const int*)d_in[0];
    const void* embed = d_in[1];
    const void* w1    = d_in[2];
    const void* b1    = d_in[3];
    const void* w2    = d_in[4];
    const void* b2    = d_in[5];
    const void* ln_g  = d_in[6];
    const void* ln_b  = d_in[7];
    const void* wk    = d_in[8];
    const void* wv    = d_in[9];
    const void* wq    = d_in[10];
    const void* wo    = d_in[11];
    const void* bo    = d_in[12];
    float* ws = (float*)d_ws;

    precompute_kernel<<<64, 64, 0, stream>>>(embed, w1, b1, w2, b2, ln_g, ln_b,
                                             wk, wv, wq, ws);
    gram_kernel<<<64, 64, 0, stream>>>(ws);
    scan_kernel<<<NB, 64, 0, stream>>>(x, ws, wo, bo, d_out);
}